// Round 1
// baseline (515.105 us; speedup 1.0000x reference)
//
#include <hip/hip_runtime.h>
#include <math.h>

#ifndef M_PI
#define M_PI 3.14159265358979323846
#endif

// Problem geometry (fixed by the reference)
#define NSLICE 16      // feature slices (slice 16 wraps to 0)
#define WW     128     // detector width
#define NANG   128     // angles
#define GP     129     // LDS pitch for raw/filtered rows (odd -> fewer conflicts)
#define AB     16      // angles per chunk
#define PAD    27      // u in [-26.4, 153.4] -> i0 in [-27,153], g1 up to 154
#define RP     185     // padded row length: indices -27..157 -> 185 words

// One block per (c,h): loads 16 rows, ramp-filters them in LDS, then
// backprojects the full 128x128 image (256 thr x 64 px, acc in VGPRs).
__global__ __launch_bounds__(256, 4)
void fbp_fused(const float* __restrict__ F, float* __restrict__ out) {
    __shared__ float s_raw[NSLICE * GP];
    __shared__ float s_g[NSLICE * GP];
    __shared__ float s_rows[AB * RP];
    __shared__ float s_h[WW];
    __shared__ float s_cs[AB];
    __shared__ float s_sn[AB];

    const int t   = threadIdx.x;
    const int blk = blockIdx.x;      // 0..1023
    const int c   = blk >> 7;        // 0..7
    const int hh  = blk & 127;       // 0..127

    // ---- stage the 16 feature rows F[s,0,c,hh,:] ----
    const float* Fb = F + (((size_t)c * 128 + hh) * 128);
    #pragma unroll
    for (int e = 0; e < 8; ++e) {
        int idx = t + 256 * e;           // 0..2047
        int s = idx >> 7, m = idx & 127;
        s_raw[s * GP + m] = Fb[(size_t)s * 131072 + m];  // s*8*128*128
    }

    // ---- ramp-filter taps: h[k] = real(ifft(|fftfreq(128)|))[k]
    // h[k] = ( sum_{j=1..63} 2j*cos(pi*j*k/64) + 64*(-1)^k ) / 16384
    if (t < WW) {
        float sum = (t & 1) ? -64.f : 64.f;
        for (int j = 1; j <= 63; ++j) {
            int mm = (j * t) & 127;      // arg reduced mod 2*pi
            sum = fmaf(2.f * (float)j, cosf((float)mm * (float)(M_PI / 64.0)), sum);
        }
        s_h[t] = sum * (1.f / 16384.f);
    }
    __syncthreads();

    // ---- circular convolution: G[s][n] = sum_m raw[s][m] * h[(n-m)&127]
    // thread t: s = t>>4, outputs n = (t&15) + 16*i  (conflict-free h reads)
    {
        const int s  = t >> 4;
        const int n0 = t & 15;
        float fa[8] = {0.f, 0.f, 0.f, 0.f, 0.f, 0.f, 0.f, 0.f};
        for (int m = 0; m < WW; ++m) {
            float rm = s_raw[s * GP + m];      // broadcast within 16-lane group
            int hb = (n0 - m) & 127;
            #pragma unroll
            for (int i = 0; i < 8; ++i) {
                int hi = (hb + 16 * i) & 127;
                fa[i] = fmaf(rm, s_h[hi], fa[i]);
            }
        }
        #pragma unroll
        for (int i = 0; i < 8; ++i)
            s_g[s * GP + n0 + 16 * i] = fa[i];
    }

    // ---- backprojection ----
    const int   Y   = t & 127;
    const int   X0  = t >> 7;                 // 0 or 1; pixel X = X0 + 2k
    const float yc  = (float)Y  - 63.5f;
    const float xc0 = (float)X0 - 63.5f;

    float acc[64];
    #pragma unroll
    for (int k = 0; k < 64; ++k) acc[k] = 0.f;

    for (int chunk = 0; chunk < NANG / AB; ++chunk) {
        __syncthreads();                      // rows buffer free to overwrite
        if (t < AB) {
            int a = chunk * AB + t;
            float th = (float)a * (float)(M_PI / 128.0);
            s_cs[t] = cosf(th);
            s_sn[t] = sinf(th);
        }
        // build AB zero-padded interpolated angle rows
        {
            const int aj     = t >> 4;        // 0..15 angle within chunk
            const int lane16 = t & 15;
            const int a  = chunk * AB + aj;
            const int i0 = a >> 3;
            const int i1 = (i0 + 1) & 15;     // slice 16 == slice 0
            const float w = (float)(a & 7) * 0.125f;
            const float* g0r = &s_g[i0 * GP];
            const float* g1r = &s_g[i1 * GP];
            float* rr = &s_rows[aj * RP];
            #pragma unroll
            for (int q = 0; q < 12; ++q) {
                int p = lane16 + 16 * q;
                if (p < RP) {
                    int ix = p - PAD;
                    float v = 0.f;
                    if ((unsigned)ix < 128u) {
                        float a0 = g0r[ix];
                        float a1 = g1r[ix];
                        v = fmaf(w, a1 - a0, a0);
                    }
                    rr[p] = v;               // zeros outside -> no bounds checks
                }
            }
        }
        __syncthreads();

        #pragma unroll 1
        for (int j = 0; j < AB; ++j) {
            const float cs = s_cs[j];
            const float sn = s_sn[j];
            float u = fmaf(xc0, cs, fmaf(yc, sn, 63.5f));
            const float du = cs + cs;        // X step is 2
            const float* rb = &s_rows[j * RP + PAD];
            #pragma unroll
            for (int k = 0; k < 64; ++k) {
                float fl = floorf(u);
                int   ii = (int)fl;          // >= -27, <= 153
                float fr = u - fl;
                float q0 = rb[ii];
                float q1 = rb[ii + 1];       // -> ds_read2_b32
                acc[k] += q0;
                acc[k] = fmaf(fr, q1 - q0, acc[k]);
                u += du;
            }
        }
    }

    // ---- write out: vol[c,hh,X,Y] * (pi/128), coalesced ----
    float* ob = out + (size_t)blk * 16384;
    const float scale = (float)(M_PI / 128.0);
    #pragma unroll
    for (int k = 0; k < 64; ++k)
        ob[t + 256 * k] = acc[k] * scale;
}

extern "C" void kernel_launch(void* const* d_in, const int* in_sizes, int n_in,
                              void* d_out, int out_size, void* d_ws, size_t ws_size,
                              hipStream_t stream) {
    const float* F = (const float*)d_in[0];
    float* out = (float*)d_out;
    fbp_fused<<<1024, 256, 0, stream>>>(F, out);
}

// Round 2
// 429.312 us; speedup vs baseline: 1.1998x; 1.1998x over previous
//
#include <hip/hip_runtime.h>
#include <math.h>

#ifndef M_PI
#define M_PI 3.14159265358979323846
#endif

// Geometry fixed by the reference
#define NSLICE 16
#define WW     128
#define NANG   128
#define GP     130    // s_g row pitch (floats)
#define AB     16     // angles per chunk
#define PAD    27     // u+PAD in [0.6, 180.4] -> ii in [0,180]
#define NE     181    // valid (p0,d) entries per row
#define NEP    184    // row stride in float2 (alignment pad)

// One block per (c, h, half-image). 256 thr, 32 px/thread, acc in VGPRs.
// Rows stored as (p0, d=p1-p0) float2 -> one ds_read_b64 + 2 VALU per sample.
__global__ __launch_bounds__(256, 4)
void fbp_fused(const float* __restrict__ F, float* __restrict__ out) {
    // overlay: phase0 {cos table, raw rows} / phase1 {padded (p0,d) rows}
    __shared__ __align__(16) char s_overlay[AB * NEP * sizeof(float2)];
    __shared__ float s_g[NSLICE][GP];
    __shared__ float s_h[WW];
    __shared__ float s_cs[NANG];
    __shared__ float s_sn[NANG];

    float*  s_cos  = (float*)s_overlay;            // [128]   (phase 0)
    float*  s_raw  = (float*)(s_overlay + 512);    // [16*129](phase 0)
    float2* s_rows = (float2*)s_overlay;           // [AB*NEP](phase 1)

    const int t   = threadIdx.x;
    const int blk = blockIdx.x;       // 0..2047
    const int q   = blk & 1;          // image half (X: q*64 .. q*64+63)
    const int hh  = (blk >> 1) & 127;
    const int c   = blk >> 8;

    // ---- phase 0a: stage the 16 feature rows F[s,0,c,hh,:], tables ----
    const float* Fb = F + (((size_t)c * 128 + hh) * 128);
    #pragma unroll
    for (int e = 0; e < 8; ++e) {
        int idx = t + 256 * e;              // 0..2047
        int s = idx >> 7, m = idx & 127;
        s_raw[s * 129 + m] = Fb[(size_t)s * 131072 + m]; // s*8*128*128
    }
    if (t < 128) {
        s_cos[t] = cosf((float)t * (float)(M_PI / 64.0)); // cos(2pi t/128)
        float th = (float)t * (float)(M_PI / 128.0);
        s_cs[t] = cosf(th);
        s_sn[t] = sinf(th);
    }
    __syncthreads();

    // ---- phase 0b: ramp taps h[k] = (64*(-1)^k + sum 2j*cos(2pi jk/128))/16384
    if (t < 128) {
        float sum = (t & 1) ? -64.f : 64.f;
        #pragma unroll
        for (int j = 1; j <= 63; ++j)
            sum = fmaf(2.f * (float)j, s_cos[(j * t) & 127], sum);
        s_h[t] = sum * (1.f / 16384.f);
    }
    __syncthreads();

    // ---- phase 0c: circular conv -> filtered slice rows s_g ----
    {
        const int s  = t >> 4;
        const int n0 = t & 15;
        float fa[8] = {0.f,0.f,0.f,0.f,0.f,0.f,0.f,0.f};
        const float* rawr = &s_raw[s * 129];
        for (int m = 0; m < WW; ++m) {
            float rm = rawr[m];
            int hb = (n0 - m) & 127;
            #pragma unroll
            for (int i = 0; i < 8; ++i)
                fa[i] = fmaf(rm, s_h[(hb + 16 * i) & 127], fa[i]);
        }
        #pragma unroll
        for (int i = 0; i < 8; ++i)
            s_g[s][n0 + 16 * i] = fa[i];
    }
    // (no barrier here: chunk-loop barrier below covers s_g writes + s_raw death)

    // ---- backprojection ----
    const int   Y  = t & 127;
    const int   xh = t >> 7;                // pixel X = q*64 + xh + 2k
    const float yc = (float)Y - 63.5f;
    const float xc = (float)(q * 64 + xh) - 63.5f;

    float acc[32];
    #pragma unroll
    for (int k = 0; k < 32; ++k) acc[k] = 0.f;

    #pragma unroll 1
    for (int ch = 0; ch < NANG / AB; ++ch) {
        __syncthreads();                    // rows buffer free; s_g visible
        // build AB zero-padded (p0,d) rows
        {
            const int aj   = t >> 4;        // angle within chunk
            const int lane = t & 15;
            const int a  = ch * AB + aj;
            const int i0 = a >> 3;
            const int i1 = (i0 + 1) & 15;   // slice 16 wraps to 0
            const float w = (float)(a & 7) * 0.125f;
            const float* g0r = s_g[i0];
            const float* g1r = s_g[i1];
            float2* rr = &s_rows[aj * NEP];
            #pragma unroll
            for (int pq = 0; pq < 12; ++pq) {
                int p = lane + 16 * pq;
                if (p < NE) {
                    int ix = p - PAD;
                    float v0 = 0.f, v1 = 0.f;
                    if ((unsigned)ix < 128u)
                        v0 = fmaf(w, g1r[ix] - g0r[ix], g0r[ix]);
                    int iy = ix + 1;
                    if ((unsigned)iy < 128u)
                        v1 = fmaf(w, g1r[iy] - g0r[iy], g0r[iy]);
                    rr[p] = make_float2(v0, v1 - v0);
                }
            }
        }
        __syncthreads();

        #pragma unroll 1
        for (int j = 0; j < AB; ++j) {
            const int a = ch * AB + j;
            const float cs = s_cs[a];
            const float sn = s_sn[a];
            const float du = cs + cs;       // X step is 2
            float u = fmaf(xc, cs, fmaf(yc, sn, (float)(63.5 + PAD)));
            const float2* rp = &s_rows[j * NEP];
            #pragma unroll
            for (int k = 0; k < 32; ++k) {
                int   ii = (int)u;                       // trunc == floor (u>0)
                float fr = __builtin_amdgcn_fractf(u);
                float2 pd = rp[ii];                      // ds_read_b64
                acc[k] = fmaf(fr, pd.y, acc[k] + pd.x);
                u += du;
            }
        }
    }

    // ---- write out: vol[c,hh,X,Y] * (pi/128), coalesced per k ----
    float* ob = out + ((size_t)(c * 128 + hh) * 16384) + q * 8192;
    const float scale = (float)(M_PI / 128.0);
    #pragma unroll
    for (int k = 0; k < 32; ++k)
        ob[k * 256 + t] = acc[k] * scale;
}

extern "C" void kernel_launch(void* const* d_in, const int* in_sizes, int n_in,
                              void* d_out, int out_size, void* d_ws, size_t ws_size,
                              hipStream_t stream) {
    const float* F = (const float*)d_in[0];
    float* out = (float*)d_out;
    fbp_fused<<<2048, 256, 0, stream>>>(F, out);
}